// Round 1
// baseline (168.724 us; speedup 1.0000x reference)
//
#include <hip/hip_runtime.h>
#include <stdint.h>

typedef unsigned short u16;
typedef __attribute__((ext_vector_type(8))) short short8;   // 8 x bf16 (4 VGPRs)
typedef __attribute__((ext_vector_type(4))) float f32x4;    // 4 x fp32 acc

typedef __attribute__((address_space(3))) uint8_t* lds_ptr_t;
typedef const __attribute__((address_space(1))) uint8_t* gbl_ptr_t;

__device__ __forceinline__ u16 f2bf(float f) {
    union { float f; uint32_t u; } v; v.f = f;
    return (u16)((v.u + (0x7FFFu + ((v.u >> 16) & 1u))) >> 16);   // RNE
}

// ---------------- P1: W2[o][j] = sum_i U[o][i] * S[i][j]  (256x64, bf16 out) ----
__global__ void k_us(const float* __restrict__ U, const float* __restrict__ S,
                     u16* __restrict__ W2) {
    int t = blockIdx.x * 256 + threadIdx.x;        // 16384 threads
    int o = t >> 6, j = t & 63;
    float acc = 0.f;
#pragma unroll 8
    for (int i = 0; i < 64; ++i) acc += U[o * 64 + i] * S[i * 64 + j];
    W2[t] = f2bf(acc);
}

// ---------------- P2: Vp = V packed in exact MFMA A-fragment order -------------
// frag(kv,tap,cc,mt): 1024 B, lane ln holds 16 B at ln*16 = A[m=mt*16+(ln&15)]
// [k = quad*8+e] with c = kv*64+cc*32+quad*8+e. One coalesced 1KB load/frag.
__global__ void k_vpack(const float* __restrict__ V, u16* __restrict__ Vp) {
    int t = blockIdx.x * 256 + threadIdx.x;        // 18432 threads (72 blocks)
    int ln = t & 63, mt = (t >> 6) & 3, cc = (t >> 8) & 1;
    int tap = (t >> 9) % 9, kv = t / 4608;
    int r = mt * 16 + (ln & 15);
    int cb = kv * 64 + cc * 32 + (ln >> 4) * 8;
    u16 tmp[8];
#pragma unroll
    for (int e = 0; e < 8; ++e)
        tmp[e] = f2bf(V[(size_t)((cb + e) * 9 + tap) * 64 + r]);
    *(uint4*)(Vp + (size_t)t * 8) = *(uint4*)tmp;
}

// ---------------- P3: coalesced LDS-tiled transpose+pad  -----------------------
// xb[b][hp][wp][c] (bf16, [16][58][58][256]) from x[b][c][h][w] fp32.
__global__ __launch_bounds__(256) void k_tr(const float* __restrict__ x,
                                            u16* __restrict__ xb) {
    __shared__ uint32_t lds[64 * 57];               // 14592 B
    int bi = blockIdx.x;                            // 16*58*2 = 1856
    int cg = bi & 1;
    int hp = (bi >> 1) % 58;
    int b  = bi / 116;
    int c0 = cg * 128;
    int tid = threadIdx.x;

    uint32_t* xbrow32 = (uint32_t*)(xb + ((size_t)(b * 58 + hp) * 58) * 256 + c0);

    if (hp == 0 || hp == 57) {                      // border row: all zeros
        for (int i = tid; i < 58 * 64; i += 256)
            xbrow32[(i >> 6) * 128 + (i & 63)] = 0u;
        return;
    }

    int h = hp - 1;
    int w = tid & 63;                               // 56 valid
    int cpq = tid >> 6;                             // 0..3
    const float* xbase = x + ((size_t)(b * 256 + c0) * 3136) + h * 56 + w;
    if (w < 56) {
#pragma unroll
        for (int k = 0; k < 16; ++k) {
            int cp = cpq * 16 + k;                  // channel pair 0..63
            float a0 = xbase[(size_t)(2 * cp) * 3136];
            float a1 = xbase[(size_t)(2 * cp + 1) * 3136];
            lds[cp * 57 + w] = (uint32_t)f2bf(a0) | ((uint32_t)f2bf(a1) << 16);
        }
    }
    __syncthreads();

    int cpair = tid & 63;
    int wpq = tid >> 6;
#pragma unroll
    for (int wp = wpq; wp < 58; wp += 4) {
        uint32_t v = (wp == 0 || wp == 57) ? 0u : lds[cpair * 57 + (wp - 1)];
        xbrow32[wp * 128 + cpair] = v;
    }
}

// ---------------- Stage A v5: one-barrier LDS conv GEMM ------------------------
// Block = 8x8 output tile (784 = 16b x 7ht x 7wt). Stage the full 10x10x256c
// halo window (51.2 KB) ONCE via global_load_lds w/ XOR-swizzled slots, then an
// 18-step K-loop per wave (K-split-4 over channels), zero barriers inside.
// v5 changes vs v4:
//   (a) stage loads are SPLIT across the 4 waves (i = kv, kv+4, ...): v4 had all
//       4 waves issuing the identical 50 loads -> 4x LDS-write + VMEM traffic.
//   (b) 3 blocks/CU (3*51.2KB = 153.6KB <= 160KB): tail 1.53 -> 1.02 rounds,
//       3 waves/SIMD to hide the stage drain. VGPR cap 168.
//   (c) XCD-chunked blockIdx swizzle (784%8==0, bijective): halo-sharing
//       neighbor tiles land on the same XCD L2.
__global__ __launch_bounds__(256, 3) void k_convA(const u16* __restrict__ xb,
                                                  const u16* __restrict__ Vp,
                                                  u16* __restrict__ y1) {
    __shared__ u16 lds[100 * 256];                  // 51200 B: [cell][512B swizzled]
    int bi0 = blockIdx.x;                           // 784 = 8 * 98
    int bi = (bi0 & 7) * 98 + (bi0 >> 3);           // XCD-chunked swizzle
    int wt = bi % 7, ht = (bi / 7) % 7, b = bi / 49;
    int h0 = ht * 8, w0 = wt * 8;
    int tid = threadIdx.x;
    int kv = tid >> 6, ln = tid & 63;
    int lane15 = ln & 15, quad = ln >> 4;

    // ---- stage: 50 x 1KB split across waves; lane j of cell fetches slice
    //      (j ^ (cell&7)). Wave kv issues i = kv, kv+4, ... (12-13 each).
    {
        int cs2 = ln >> 5;                          // which of the 2 cells/instr
        int j   = ln & 31;
        int cell = 2 * kv + cs2;
        int rr = 0, wp = cell;                      // cell <= 7 < 10
        const u16* gw = xb + (((size_t)(b * 58 + h0)) * 58 + w0) * 256;
        char* lb = (char*)lds;
        for (int i = kv; i < 50; i += 4) {
            const u16* g = gw + (rr * 58 + wp) * 256 + ((j ^ (cell & 7)) << 3);
            __builtin_amdgcn_global_load_lds((gbl_ptr_t)g,
                                             (lds_ptr_t)(lb + i * 1024), 16, 0, 0);
            cell += 8; wp += 8;
            if (wp >= 10) { wp -= 10; rr += 1; }
        }
    }
    __syncthreads();

    // ---- K-loop: 9 taps x 2 cc (32c each) = 18 MFMA k-steps, no barriers ----
    int dh = lane15 >> 3, dw = lane15 & 7;
    int cell00 = dh * 10 + dw;
    int jbase = (kv << 3) + quad;                   // j' = kv*8 + cc*4 + quad
    const char* lb = (const char*)lds;

    f32x4 acc[4][4];
#pragma unroll
    for (int mt = 0; mt < 4; ++mt)
#pragma unroll
        for (int nt = 0; nt < 4; ++nt) acc[mt][nt] = (f32x4){0.f, 0.f, 0.f, 0.f};

#pragma unroll
    for (int tap = 0; tap < 9; ++tap) {
        const int di = tap / 3, dj = tap % 3;
#pragma unroll
        for (int cc = 0; cc < 2; ++cc) {
            const u16* ab = Vp + ((size_t)(((kv * 9 + tap) * 2 + cc) * 4) * 512)
                          + ln * 8;
            short8 a[4];
#pragma unroll
            for (int mt = 0; mt < 4; ++mt)
                a[mt] = *(const short8*)(ab + mt * 512);
            int jj = jbase + (cc << 2);
            short8 bv[4];
#pragma unroll
            for (int nt = 0; nt < 4; ++nt) {
                int cell = cell00 + nt * 20 + di * 10 + dj;
                int off = cell * 512 + ((jj ^ (cell & 7)) << 4);
                bv[nt] = *(const short8*)(lb + off);
            }
#pragma unroll
            for (int mt = 0; mt < 4; ++mt)
#pragma unroll
                for (int nt = 0; nt < 4; ++nt)
                    acc[mt][nt] = __builtin_amdgcn_mfma_f32_16x16x32_bf16(
                        a[mt], bv[nt], acc[mt][nt], 0, 0, 0);
        }
    }

    // ---- 4-way K-split reduction (reuse x-LDS; 32KB <= 51.2KB) ----
    __syncthreads();                                // all ds_reads of x done
    f32x4* red = (f32x4*)lds;
    if (kv & 1) {                                   // kv 1 -> red[0..15], 3 -> [16..31]
        f32x4* dst = red + ((kv >> 1) * 16) * 64;
#pragma unroll
        for (int f = 0; f < 16; ++f) dst[f * 64 + ln] = acc[f >> 2][f & 3];
    }
    __syncthreads();
    if (kv == 0) {
#pragma unroll
        for (int f = 0; f < 16; ++f) acc[f >> 2][f & 3] += red[f * 64 + ln];
    } else if (kv == 2) {
#pragma unroll
        for (int f = 0; f < 16; ++f) red[(16 + f) * 64 + ln] += acc[f >> 2][f & 3];
    }
    __syncthreads();
    if (kv == 0) {
#pragma unroll
        for (int mt = 0; mt < 4; ++mt)
#pragma unroll
            for (int nt = 0; nt < 4; ++nt) {
                f32x4 v = acc[mt][nt] + red[(16 + mt * 4 + nt) * 64 + ln];
                int oh = nt * 2 + dh, ow = dw;
                int l = b * 3136 + (h0 + oh) * 56 + (w0 + ow);
                uint2 pv;
                pv.x = (uint32_t)f2bf(v[0]) | ((uint32_t)f2bf(v[1]) << 16);
                pv.y = (uint32_t)f2bf(v[2]) | ((uint32_t)f2bf(v[3]) << 16);
                *(uint2*)(y1 + ((size_t)l << 6) + mt * 16 + quad * 4) = pv;
            }
    }
}

// ---------------- Stage B: out[b][o][l] = W2[o][:] . y1[b][l][:] + bias[o] -----
__global__ __launch_bounds__(256) void k_gemmB(const u16* __restrict__ y1,
                                               const u16* __restrict__ W2,
                                               const float* __restrict__ bias,
                                               float* __restrict__ out) {
    __shared__ u16 lds_y[64 * 72];                  // 9216 B
    int bi = blockIdx.x;                            // 784 = 16*49
    int b = bi % 16, lt = bi / 16;
    int l0 = lt * 64;
    int tid = threadIdx.x;
    int wv = tid >> 6, ln = tid & 63;
    int lane15 = ln & 15, quad = ln >> 4;

    for (int idx = tid; idx < 512; idx += 256) {
        int q = idx & 7, n = idx >> 3;
        uint4 v = *(const uint4*)(y1 + (((size_t)(b * 3136 + l0 + n)) << 6) + q * 8);
        *(uint4*)&lds_y[n * 72 + q * 8] = v;
    }
    __syncthreads();

    f32x4 acc[4][4];
#pragma unroll
    for (int mt = 0; mt < 4; ++mt)
#pragma unroll
        for (int nt = 0; nt < 4; ++nt) acc[mt][nt] = (f32x4){0.f, 0.f, 0.f, 0.f};

    int o0 = wv * 64;
#pragma unroll
    for (int ks = 0; ks < 64; ks += 32) {
        short8 a[4];
#pragma unroll
        for (int mt = 0; mt < 4; ++mt)
            a[mt] = *(const short8*)(W2 + (size_t)(o0 + mt * 16 + lane15) * 64
                                     + ks + quad * 8);
#pragma unroll
        for (int nt = 0; nt < 4; ++nt) {
            short8 bv = *(const short8*)&lds_y[(nt * 16 + lane15) * 72 + ks + quad * 8];
#pragma unroll
            for (int mt = 0; mt < 4; ++mt)
                acc[mt][nt] = __builtin_amdgcn_mfma_f32_16x16x32_bf16(a[mt], bv, acc[mt][nt], 0, 0, 0);
        }
    }

#pragma unroll
    for (int mt = 0; mt < 4; ++mt) {
        int ob = o0 + mt * 16 + quad * 4;
#pragma unroll
        for (int reg = 0; reg < 4; ++reg) {
            int o = ob + reg;
            float bvl = bias[o];
            float* orow = out + ((size_t)(b * 256 + o)) * 3136 + l0 + lane15;
#pragma unroll
            for (int nt = 0; nt < 4; ++nt)
                orow[nt * 16] = acc[mt][nt][reg] + bvl;
        }
    }
}

extern "C" void kernel_launch(void* const* d_in, const int* in_sizes, int n_in,
                              void* d_out, int out_size, void* d_ws, size_t ws_size,
                              hipStream_t stream) {
    const float* x    = (const float*)d_in[0];   // [16,256,56,56]
    const float* U    = (const float*)d_in[1];   // [256,64]
    const float* S    = (const float*)d_in[2];   // [64,64]
    const float* V    = (const float*)d_in[3];   // [2304,64]
    const float* bias = (const float*)d_in[4];   // [256]
    float* out = (float*)d_out;                  // [16,256,56,56] fp32

    char* ws = (char*)d_ws;
    u16* xb = (u16*)ws;                                   // 27,557,888 B
    u16* Vp = (u16*)(ws + 27557888);                      //    294,912 B
    u16* W2 = (u16*)(ws + 27557888 + 294912);             //     32,768 B
    u16* y1 = (u16*)(ws + 27557888 + 294912 + 32768);     //  6,422,528 B

    k_us   <<<64,   256, 0, stream>>>(U, S, W2);
    k_vpack<<<72,   256, 0, stream>>>(V, Vp);
    k_tr   <<<1856, 256, 0, stream>>>(x, xb);
    k_convA<<<784,  256, 0, stream>>>(xb, Vp, y1);
    k_gemmB<<<784,  256, 0, stream>>>(y1, W2, bias, out);
}

// Round 2
// 161.814 us; speedup vs baseline: 1.0427x; 1.0427x over previous
//
#include <hip/hip_runtime.h>
#include <stdint.h>

typedef unsigned short u16;
typedef __attribute__((ext_vector_type(8))) short short8;   // 8 x bf16 (4 VGPRs)
typedef __attribute__((ext_vector_type(4))) float f32x4;    // 4 x fp32 acc

__device__ __forceinline__ u16 f2bf(float f) {
    union { float f; uint32_t u; } v; v.f = f;
    return (u16)((v.u + (0x7FFFu + ((v.u >> 16) & 1u))) >> 16);   // RNE
}

// ---------------- P1+P2 merged: W2 = U*S (bf16) | Vp = MFMA-packed V -----------
// blocks 0..63: W2[o][j] = sum_i U[o][i]*S[i][j]   (256x64)
// blocks 64..135: Vp frag(kv,tap,cc,mt): 1KB, lane ln holds 16B at ln*16 =
//   A[m=mt*16+(ln&15)][k=quad*8+e], c = kv*64+cc*32+quad*8+e.
__global__ void k_prep(const float* __restrict__ U, const float* __restrict__ S,
                       u16* __restrict__ W2,
                       const float* __restrict__ V, u16* __restrict__ Vp) {
    int bx = blockIdx.x;
    if (bx < 64) {
        int t = bx * 256 + threadIdx.x;                // 16384 threads
        int o = t >> 6, j = t & 63;
        float acc = 0.f;
#pragma unroll 8
        for (int i = 0; i < 64; ++i) acc += U[o * 64 + i] * S[i * 64 + j];
        W2[t] = f2bf(acc);
    } else {
        int t = (bx - 64) * 256 + threadIdx.x;         // 18432 threads (72 blocks)
        int ln = t & 63, mt = (t >> 6) & 3, cc = (t >> 8) & 1;
        int tap = (t >> 9) % 9, kv = t / 4608;
        int r = mt * 16 + (ln & 15);
        int cb = kv * 64 + cc * 32 + (ln >> 4) * 8;
        u16 tmp[8];
#pragma unroll
        for (int e = 0; e < 8; ++e)
            tmp[e] = f2bf(V[(size_t)((cb + e) * 9 + tap) * 64 + r]);
        *(uint4*)(Vp + (size_t)t * 8) = *(uint4*)tmp;
    }
}

// ---------------- P3: coalesced LDS-tiled transpose+pad  -----------------------
// xb[b][hp][wp][c] (bf16, [16][58][58][256]) from x[b][c][h][w] fp32.
__global__ __launch_bounds__(256) void k_tr(const float* __restrict__ x,
                                            u16* __restrict__ xb) {
    __shared__ uint32_t lds[64 * 57];               // 14592 B
    int bi = blockIdx.x;                            // 16*58*2 = 1856
    int cg = bi & 1;
    int hp = (bi >> 1) % 58;
    int b  = bi / 116;
    int c0 = cg * 128;
    int tid = threadIdx.x;

    uint32_t* xbrow32 = (uint32_t*)(xb + ((size_t)(b * 58 + hp) * 58) * 256 + c0);

    if (hp == 0 || hp == 57) {                      // border row: all zeros
        for (int i = tid; i < 58 * 64; i += 256)
            xbrow32[(i >> 6) * 128 + (i & 63)] = 0u;
        return;
    }

    int h = hp - 1;
    int w = tid & 63;                               // 56 valid
    int cpq = tid >> 6;                             // 0..3
    const float* xbase = x + ((size_t)(b * 256 + c0) * 3136) + h * 56 + w;
    if (w < 56) {
#pragma unroll
        for (int k = 0; k < 16; ++k) {
            int cp = cpq * 16 + k;                  // channel pair 0..63
            float a0 = xbase[(size_t)(2 * cp) * 3136];
            float a1 = xbase[(size_t)(2 * cp + 1) * 3136];
            lds[cp * 57 + w] = (uint32_t)f2bf(a0) | ((uint32_t)f2bf(a1) << 16);
        }
    }
    __syncthreads();

    int cpair = tid & 63;
    int wpq = tid >> 6;
#pragma unroll
    for (int wp = wpq; wp < 58; wp += 4) {
        uint32_t v = (wp == 0 || wp == 57) ? 0u : lds[cpair * 57 + (wp - 1)];
        xbrow32[wp * 128 + cpair] = v;
    }
}

// ---------------- Stage A v6: zero-stage L2-streaming conv GEMM ----------------
// Block = 8x8 output tile (784 = 16b x 7ht x 7wt), 4 waves, K-split-4 over kv.
// NO LDS staging: B-fragments are loaded straight from xb (channel-contiguous,
// 64B/pixel coalesced dwordx4) and hit L2 (each 50KB window re-read ~4.3x,
// resident in 4MB/XCD).  Row-overlap reuse: per (cc,dj) one 9-entry register
// column bvr[rr] (rows rr=0..8 at col dw+dj) serves all (di,nt): cell row
// nt*2+dh+di == rr+dh.  A-frags (Vp) are 1KB coalesced L2-hot loads, each read
// once per block (optimal).  No stage barrier, no convoy: 126 independent vmem
// loads/wave of ILP + ~12 waves/CU of TLP.  Only the 4-way K-split reduction
// (dedicated 32KB LDS) synchronizes, with 2 barriers.
__global__ __launch_bounds__(256) void k_convA(const u16* __restrict__ xb,
                                               const u16* __restrict__ Vp,
                                               u16* __restrict__ y1) {
    __shared__ f32x4 red[32 * 64];                  // 32768 B reduction scratch
    int bi = blockIdx.x;                            // 784
    int wt = bi % 7, ht = (bi / 7) % 7, b = bi / 49;
    int h0 = ht * 8, w0 = wt * 8;
    int tid = threadIdx.x;
    int kv = tid >> 6, ln = tid & 63;
    int lane15 = ln & 15, quad = ln >> 4;
    int dh = lane15 >> 3, dw = lane15 & 7;

    // B base: pixel (h0+dh, w0+dw), channel kv*64 + quad*8; +cc*32 +(rr*58+dj)*256
    const u16* xw = xb + (((size_t)(b * 58 + h0 + dh)) * 58 + (w0 + dw)) * 256
                  + kv * 64 + quad * 8;
    // A base: frag(kv,tap,cc,mt) at ((((kv*9+tap)*2+cc)*4+mt)*512 + ln*8
    const u16* ap = Vp + ((size_t)(kv * 9 * 2 * 4)) * 512 + ln * 8;

    f32x4 acc[4][4];
#pragma unroll
    for (int mt = 0; mt < 4; ++mt)
#pragma unroll
        for (int nt = 0; nt < 4; ++nt) acc[mt][nt] = (f32x4){0.f, 0.f, 0.f, 0.f};

#pragma unroll
    for (int cc = 0; cc < 2; ++cc) {
#pragma unroll
        for (int dj = 0; dj < 3; ++dj) {
            short8 bvr[9];                           // rows 0..8 at col dw+dj
#pragma unroll
            for (int rr = 0; rr < 9; ++rr)
                bvr[rr] = *(const short8*)(xw + cc * 32
                                           + ((size_t)(rr * 58 + dj)) * 256);
#pragma unroll
            for (int di = 0; di < 3; ++di) {
                int tap = di * 3 + dj;
                short8 a[4];
#pragma unroll
                for (int mt = 0; mt < 4; ++mt)
                    a[mt] = *(const short8*)(ap
                              + ((size_t)((tap * 2 + cc) * 4 + mt)) * 512);
#pragma unroll
                for (int nt = 0; nt < 4; ++nt)
#pragma unroll
                    for (int mt = 0; mt < 4; ++mt)
                        acc[mt][nt] = __builtin_amdgcn_mfma_f32_16x16x32_bf16(
                            a[mt], bvr[nt * 2 + di], acc[mt][nt], 0, 0, 0);
            }
        }
    }

    // ---- 4-way K-split reduction (dedicated red[]; 2 barriers) ----
    if (kv & 1) {                                   // kv 1 -> red[0..15], 3 -> [16..31]
        f32x4* dst = red + ((kv >> 1) * 16) * 64;
#pragma unroll
        for (int f = 0; f < 16; ++f) dst[f * 64 + ln] = acc[f >> 2][f & 3];
    }
    __syncthreads();
    if (kv == 0) {
#pragma unroll
        for (int f = 0; f < 16; ++f) acc[f >> 2][f & 3] += red[f * 64 + ln];
    } else if (kv == 2) {
#pragma unroll
        for (int f = 0; f < 16; ++f) red[(16 + f) * 64 + ln] += acc[f >> 2][f & 3];
    }
    __syncthreads();
    if (kv == 0) {
#pragma unroll
        for (int mt = 0; mt < 4; ++mt)
#pragma unroll
            for (int nt = 0; nt < 4; ++nt) {
                f32x4 v = acc[mt][nt] + red[(16 + mt * 4 + nt) * 64 + ln];
                int oh = nt * 2 + dh, ow = dw;
                int l = b * 3136 + (h0 + oh) * 56 + (w0 + ow);
                uint2 pv;
                pv.x = (uint32_t)f2bf(v[0]) | ((uint32_t)f2bf(v[1]) << 16);
                pv.y = (uint32_t)f2bf(v[2]) | ((uint32_t)f2bf(v[3]) << 16);
                *(uint2*)(y1 + ((size_t)l << 6) + mt * 16 + quad * 4) = pv;
            }
    }
}

// ---------------- Stage B: out[b][o][l] = W2[o][:] . y1[b][l][:] + bias[o] -----
__global__ __launch_bounds__(256) void k_gemmB(const u16* __restrict__ y1,
                                               const u16* __restrict__ W2,
                                               const float* __restrict__ bias,
                                               float* __restrict__ out) {
    __shared__ u16 lds_y[64 * 72];                  // 9216 B
    int bi = blockIdx.x;                            // 784 = 16*49
    int b = bi % 16, lt = bi / 16;
    int l0 = lt * 64;
    int tid = threadIdx.x;
    int wv = tid >> 6, ln = tid & 63;
    int lane15 = ln & 15, quad = ln >> 4;

    for (int idx = tid; idx < 512; idx += 256) {
        int q = idx & 7, n = idx >> 3;
        uint4 v = *(const uint4*)(y1 + (((size_t)(b * 3136 + l0 + n)) << 6) + q * 8);
        *(uint4*)&lds_y[n * 72 + q * 8] = v;
    }
    __syncthreads();

    f32x4 acc[4][4];
#pragma unroll
    for (int mt = 0; mt < 4; ++mt)
#pragma unroll
        for (int nt = 0; nt < 4; ++nt) acc[mt][nt] = (f32x4){0.f, 0.f, 0.f, 0.f};

    int o0 = wv * 64;
#pragma unroll
    for (int ks = 0; ks < 64; ks += 32) {
        short8 a[4];
#pragma unroll
        for (int mt = 0; mt < 4; ++mt)
            a[mt] = *(const short8*)(W2 + (size_t)(o0 + mt * 16 + lane15) * 64
                                     + ks + quad * 8);
#pragma unroll
        for (int nt = 0; nt < 4; ++nt) {
            short8 bv = *(const short8*)&lds_y[(nt * 16 + lane15) * 72 + ks + quad * 8];
#pragma unroll
            for (int mt = 0; mt < 4; ++mt)
                acc[mt][nt] = __builtin_amdgcn_mfma_f32_16x16x32_bf16(a[mt], bv, acc[mt][nt], 0, 0, 0);
        }
    }

#pragma unroll
    for (int mt = 0; mt < 4; ++mt) {
        int ob = o0 + mt * 16 + quad * 4;
#pragma unroll
        for (int reg = 0; reg < 4; ++reg) {
            int o = ob + reg;
            float bvl = bias[o];
            float* orow = out + ((size_t)(b * 256 + o)) * 3136 + l0 + lane15;
#pragma unroll
            for (int nt = 0; nt < 4; ++nt)
                orow[nt * 16] = acc[mt][nt][reg] + bvl;
        }
    }
}

extern "C" void kernel_launch(void* const* d_in, const int* in_sizes, int n_in,
                              void* d_out, int out_size, void* d_ws, size_t ws_size,
                              hipStream_t stream) {
    const float* x    = (const float*)d_in[0];   // [16,256,56,56]
    const float* U    = (const float*)d_in[1];   // [256,64]
    const float* S    = (const float*)d_in[2];   // [64,64]
    const float* V    = (const float*)d_in[3];   // [2304,64]
    const float* bias = (const float*)d_in[4];   // [256]
    float* out = (float*)d_out;                  // [16,256,56,56] fp32

    char* ws = (char*)d_ws;
    u16* xb = (u16*)ws;                                   // 27,557,888 B
    u16* Vp = (u16*)(ws + 27557888);                      //    294,912 B
    u16* W2 = (u16*)(ws + 27557888 + 294912);             //     32,768 B
    u16* y1 = (u16*)(ws + 27557888 + 294912 + 32768);     //  6,422,528 B

    k_prep <<<136,  256, 0, stream>>>(U, S, W2, V, Vp);
    k_tr   <<<1856, 256, 0, stream>>>(x, xb);
    k_convA<<<784,  256, 0, stream>>>(xb, Vp, y1);
    k_gemmB<<<784,  256, 0, stream>>>(y1, W2, bias, out);
}